// Round 7
// baseline (262.770 us; speedup 1.0000x reference)
//
#include <hip/hip_runtime.h>
#include <cmath>

// Local contrast normalization — barrier-free wave-streaming, v2 (more TLP).
// x: [64,512,512,1] f32; 9x9 Gaussian (separable, center 4.5), SAME zero pad;
// out = keep ? d/sqrt(conv(d^2)) : d, keep = sqrt(n2) > 0.5 <=> n2 > 0.25.
//
// One wave (64 lanes) owns a full 512-px row: 8 px = 2 float4 per lane.
// Strip = 8 output rows, 24 pipeline steps (rows R0-8 .. R0+15).
// NO LDS, NO barriers. Horizontal d-halo (+-4 px) via intra-wave shuffles.
// Rings in registers, all indices static:
//   hx[8] (+current = 9 taps), q[8] (+current), d[4] (output-row delay).
// 4096 blocks x 1 wave = 16 waves/CU (VGPR <= 128 required -> lb(64,4)).

struct W9 { float w[9]; };

#define HW    512
#define SROWS 8

__device__ __forceinline__ float4 f4scale(float s, float4 a) {
    return float4{s * a.x, s * a.y, s * a.z, s * a.w};
}
__device__ __forceinline__ float4 f4fma(float s, float4 a, float4 acc) {
    return float4{fmaf(s, a.x, acc.x), fmaf(s, a.y, acc.y),
                  fmaf(s, a.z, acc.z), fmaf(s, a.w, acc.w)};
}

// 9-tap conv over a 16-float window -> 8 outputs (o[k] = sum_j w[j]*X[k+j])
__device__ __forceinline__ void conv9_8(const float X[16], const float* w,
                                        float4& o0, float4& o1) {
    float o[8];
#pragma unroll
    for (int k = 0; k < 8; ++k) {
        float a = w[0] * X[k];
#pragma unroll
        for (int j = 1; j < 9; ++j) a = fmaf(w[j], X[k + j], a);
        o[k] = a;
    }
    o0 = float4{o[0], o[1], o[2], o[3]};
    o1 = float4{o[4], o[5], o[6], o[7]};
}

// vertical 9-tap from 8-deep ring + current row
#define VRING9(ring0, ring1, ppv, cur0, cur1, out0, out1)                \
    {                                                                    \
        out0 = f4scale(w[8], cur0);                                      \
        out1 = f4scale(w[8], cur1);                                      \
        _Pragma("unroll") for (int i_ = 0; i_ < 8; ++i_) {               \
            out0 = f4fma(w[i_], ring0[((ppv) + i_) & 7], out0);          \
            out1 = f4fma(w[i_], ring1[((ppv) + i_) & 7], out1);          \
        }                                                                \
    }

// stage A: hv = horizontal conv of x row r (zero outside image)
#define STAGE_A(r, hv0, hv1)                                             \
    {                                                                    \
        hv0 = z4; hv1 = z4;                                              \
        if ((unsigned)(r) < HW) {                                        \
            const float4* row_ =                                         \
                reinterpret_cast<const float4*>(xb + (size_t)(r) * HW);  \
            float4 a_ = pl ? row_[c2 - 1] : z4;                          \
            float4 b_ = row_[c2];                                        \
            float4 g_ = row_[c2 + 1];                                    \
            float4 e_ = pr ? row_[c2 + 2] : z4;                          \
            const float X_[16] = {a_.x, a_.y, a_.z, a_.w,                \
                                  b_.x, b_.y, b_.z, b_.w,                \
                                  g_.x, g_.y, g_.z, g_.w,                \
                                  e_.x, e_.y, e_.z, e_.w};               \
            conv9_8(X_, w, hv0, hv1);                                    \
        }                                                                \
    }

// stage B: mean(rd) = v-conv(hx ring + hv); d = x(rd) - mean (0 outside)
#define STAGE_B(ppv, rd, hv0, hv1, d0_, d1_)                             \
    {                                                                    \
        d0_ = z4; d1_ = z4;                                              \
        if ((unsigned)(rd) < HW) {                                       \
            float4 m0_, m1_;                                             \
            VRING9(hx0, hx1, ppv, hv0, hv1, m0_, m1_);                   \
            const float4* rowd_ =                                        \
                reinterpret_cast<const float4*>(xb + (size_t)(rd) * HW); \
            float4 x0_ = rowd_[c2], x1_ = rowd_[c2 + 1];                 \
            d0_ = float4{x0_.x - m0_.x, x0_.y - m0_.y,                   \
                         x0_.z - m0_.z, x0_.w - m0_.w};                  \
            d1_ = float4{x1_.x - m1_.x, x1_.y - m1_.y,                   \
                         x1_.z - m1_.z, x1_.w - m1_.w};                  \
        }                                                                \
    }

// stage C: h2v = h-conv(d^2); halo f4s via intra-wave shuffles
#define STAGE_C(d0_, d1_, h2v0, h2v1)                                    \
    {                                                                    \
        float4 dl_;                                                      \
        dl_.x = __shfl_up((d1_).x, 1);                                   \
        dl_.y = __shfl_up((d1_).y, 1);                                   \
        dl_.z = __shfl_up((d1_).z, 1);                                   \
        dl_.w = __shfl_up((d1_).w, 1);                                   \
        if (c == 0) dl_ = z4;                                            \
        float4 dr_;                                                      \
        dr_.x = __shfl_down((d0_).x, 1);                                 \
        dr_.y = __shfl_down((d0_).y, 1);                                 \
        dr_.z = __shfl_down((d0_).z, 1);                                 \
        dr_.w = __shfl_down((d0_).w, 1);                                 \
        if (c == 63) dr_ = z4;                                           \
        const float Xs_[16] = {                                          \
            dl_.x * dl_.x, dl_.y * dl_.y, dl_.z * dl_.z, dl_.w * dl_.w,  \
            (d0_).x * (d0_).x, (d0_).y * (d0_).y,                        \
            (d0_).z * (d0_).z, (d0_).w * (d0_).w,                        \
            (d1_).x * (d1_).x, (d1_).y * (d1_).y,                        \
            (d1_).z * (d1_).z, (d1_).w * (d1_).w,                        \
            dr_.x * dr_.x, dr_.y * dr_.y, dr_.z * dr_.z, dr_.w * dr_.w}; \
        conv9_8(Xs_, w, h2v0, h2v1);                                     \
    }

__global__ __launch_bounds__(64, 4) void lcn_kernel(const float* __restrict__ x,
                                                    float* __restrict__ out,
                                                    W9 wts) {
    const int c = threadIdx.x;          // lane 0..63, owns f4 cols 2c, 2c+1
    const int c2 = 2 * c;
    const bool pl = (c > 0), pr = (c < 63);

    // XCD swizzle: 4096 blocks = 8 XCDs x 512; 8 images per XCD, all 64
    // strips of an image co-resident on one XCD -> halo rows L2-shared.
    const int p = blockIdx.x;
    const int lid = (p & 7) * 512 + (p >> 3);
    const int img = lid >> 6;           // 0..63
    const int strip = lid & 63;         // 0..63
    const int R0 = strip * SROWS;

    const float* xb = x + (size_t)img * HW * HW;
    float* ob = out + (size_t)img * HW * HW;

    float w[9];
#pragma unroll
    for (int i = 0; i < 9; ++i) w[i] = wts.w[i];
    const float4 z4 = {0.f, 0.f, 0.f, 0.f};

    float4 hx0[8], hx1[8];   // h-conv(x) ring
    float4 q0[8], q1[8];     // h-conv(d^2) ring
    float4 dg0[4], dg1[4];   // d ring (4-step delay to output row)

    // ---- phase 1 (s = 0..7): stage A only; fill hx ring ----
#pragma unroll
    for (int pp = 0; pp < 8; ++pp) {
        const int r = R0 - 8 + pp;
        float4 hv0, hv1;
        STAGE_A(r, hv0, hv1);
        hx0[pp] = hv0; hx1[pp] = hv1;
    }

    // ---- phase 2 (s = 8..15): A + B + C; fill q ring and d ring ----
#pragma unroll
    for (int pp = 0; pp < 8; ++pp) {
        const int r = R0 + pp;          // s = 8+pp, ring phase = pp
        float4 hv0, hv1;
        STAGE_A(r, hv0, hv1);
        float4 d0, d1;
        STAGE_B(pp, r - 4, hv0, hv1, d0, d1);
        dg0[pp & 3] = d0; dg1[pp & 3] = d1;
        hx0[pp] = hv0; hx1[pp] = hv1;
        float4 h2v0, h2v1;
        STAGE_C(d0, d1, h2v0, h2v1);
        q0[pp] = h2v0; q1[pp] = h2v1;
    }

    // ---- phase 3 (s = 16..23): full pipeline, one output row per step ----
#pragma unroll
    for (int pp = 0; pp < 8; ++pp) {
        const int r = R0 + 8 + pp;      // s = 16+pp, ring phase = pp
        float4 hv0, hv1;
        STAGE_A(r, hv0, hv1);
        float4 d0, d1;
        STAGE_B(pp, r - 4, hv0, hv1, d0, d1);
        // read d(ro) (written 4 steps ago) BEFORE overwriting the slot
        float4 do0 = dg0[pp & 3], do1 = dg1[pp & 3];
        dg0[pp & 3] = d0; dg1[pp & 3] = d1;
        hx0[pp] = hv0; hx1[pp] = hv1;
        float4 h2v0, h2v1;
        STAGE_C(d0, d1, h2v0, h2v1);
        // stage D: n2(ro) = v-conv(q ring + h2v); normalize; store
        {
            float4 n0, n1;
            VRING9(q0, q1, pp, h2v0, h2v1, n0, n1);
            const int ro = r - 8;       // in [R0, R0+8)
            float4 o0, o1;
            o0.x = (n0.x > 0.25f) ? do0.x * rsqrtf(n0.x) : do0.x;
            o0.y = (n0.y > 0.25f) ? do0.y * rsqrtf(n0.y) : do0.y;
            o0.z = (n0.z > 0.25f) ? do0.z * rsqrtf(n0.z) : do0.z;
            o0.w = (n0.w > 0.25f) ? do0.w * rsqrtf(n0.w) : do0.w;
            o1.x = (n1.x > 0.25f) ? do1.x * rsqrtf(n1.x) : do1.x;
            o1.y = (n1.y > 0.25f) ? do1.y * rsqrtf(n1.y) : do1.y;
            o1.z = (n1.z > 0.25f) ? do1.z * rsqrtf(n1.z) : do1.z;
            o1.w = (n1.w > 0.25f) ? do1.w * rsqrtf(n1.w) : do1.w;
            float4* rowo = reinterpret_cast<float4*>(ob + (size_t)ro * HW);
            rowo[c2] = o0;
            rowo[c2 + 1] = o1;
        }
        q0[pp] = h2v0; q1[pp] = h2v1;
    }
}

static W9 make_w() {
    // reference: sigmah = 9/6, exponent divides by 2*sigmah = 3.0;
    // taps centered at 4.5 (asymmetric); separable: w1 = g1 / sum(g1).
    double g[9], sum = 0.0;
    for (int i = 0; i < 9; ++i) {
        double off = (double)i - 4.5;
        g[i] = exp(-(off * off) / 3.0);
        sum += g[i];
    }
    W9 r;
    for (int i = 0; i < 9; ++i) r.w[i] = (float)(g[i] / sum);
    return r;
}

extern "C" void kernel_launch(void* const* d_in, const int* in_sizes, int n_in,
                              void* d_out, int out_size, void* d_ws, size_t ws_size,
                              hipStream_t stream) {
    const float* x = (const float*)d_in[0];
    float* out = (float*)d_out;
    W9 w = make_w();
    // 64 images x 64 strips of 8 rows = 4096 blocks, 64 threads (1 wave) each.
    lcn_kernel<<<dim3(4096), dim3(64), 0, stream>>>(x, out, w);
}

// Round 8
// 112.882 us; speedup vs baseline: 2.3278x; 2.3278x over previous
//
#include <hip/hip_runtime.h>
#include <cmath>

// Local contrast normalization — barrier-free wave-streaming, v3.
// Same structure as r7 (SROWS=8, 4096 single-wave blocks) but with the
// r6-proven __launch_bounds__(64,2): r7's (64,4) forced the register
// allocator to spill all rings to scratch (VGPR 124->64, WRITE_SIZE
// 64->318 MB). 124 VGPR already permits 4 waves/SIMD in HW; the hint
// only constrained the allocator.
//
// x: [64,512,512,1] f32; 9x9 Gaussian (separable, center 4.5), SAME zero pad;
// out = keep ? d/sqrt(conv(d^2)) : d, keep = sqrt(n2) > 0.5 <=> n2 > 0.25.
// One wave owns a full 512-px row: 8 px = 2 float4 per lane.
// NO LDS, NO barriers. Horizontal d-halo (+-4 px) via intra-wave shuffles.

struct W9 { float w[9]; };

#define HW    512
#define SROWS 8

__device__ __forceinline__ float4 f4scale(float s, float4 a) {
    return float4{s * a.x, s * a.y, s * a.z, s * a.w};
}
__device__ __forceinline__ float4 f4fma(float s, float4 a, float4 acc) {
    return float4{fmaf(s, a.x, acc.x), fmaf(s, a.y, acc.y),
                  fmaf(s, a.z, acc.z), fmaf(s, a.w, acc.w)};
}

// 9-tap conv over a 16-float window -> 8 outputs (o[k] = sum_j w[j]*X[k+j])
__device__ __forceinline__ void conv9_8(const float X[16], const float* w,
                                        float4& o0, float4& o1) {
    float o[8];
#pragma unroll
    for (int k = 0; k < 8; ++k) {
        float a = w[0] * X[k];
#pragma unroll
        for (int j = 1; j < 9; ++j) a = fmaf(w[j], X[k + j], a);
        o[k] = a;
    }
    o0 = float4{o[0], o[1], o[2], o[3]};
    o1 = float4{o[4], o[5], o[6], o[7]};
}

// vertical 9-tap from 8-deep ring + current row
#define VRING9(ring0, ring1, ppv, cur0, cur1, out0, out1)                \
    {                                                                    \
        out0 = f4scale(w[8], cur0);                                      \
        out1 = f4scale(w[8], cur1);                                      \
        _Pragma("unroll") for (int i_ = 0; i_ < 8; ++i_) {               \
            out0 = f4fma(w[i_], ring0[((ppv) + i_) & 7], out0);          \
            out1 = f4fma(w[i_], ring1[((ppv) + i_) & 7], out1);          \
        }                                                                \
    }

// stage A: hv = horizontal conv of x row r (zero outside image)
#define STAGE_A(r, hv0, hv1)                                             \
    {                                                                    \
        hv0 = z4; hv1 = z4;                                              \
        if ((unsigned)(r) < HW) {                                        \
            const float4* row_ =                                         \
                reinterpret_cast<const float4*>(xb + (size_t)(r) * HW);  \
            float4 a_ = pl ? row_[c2 - 1] : z4;                          \
            float4 b_ = row_[c2];                                        \
            float4 g_ = row_[c2 + 1];                                    \
            float4 e_ = pr ? row_[c2 + 2] : z4;                          \
            const float X_[16] = {a_.x, a_.y, a_.z, a_.w,                \
                                  b_.x, b_.y, b_.z, b_.w,                \
                                  g_.x, g_.y, g_.z, g_.w,                \
                                  e_.x, e_.y, e_.z, e_.w};               \
            conv9_8(X_, w, hv0, hv1);                                    \
        }                                                                \
    }

// stage B: mean(rd) = v-conv(hx ring + hv); d = x(rd) - mean (0 outside)
#define STAGE_B(ppv, rd, hv0, hv1, d0_, d1_)                             \
    {                                                                    \
        d0_ = z4; d1_ = z4;                                              \
        if ((unsigned)(rd) < HW) {                                       \
            float4 m0_, m1_;                                             \
            VRING9(hx0, hx1, ppv, hv0, hv1, m0_, m1_);                   \
            const float4* rowd_ =                                        \
                reinterpret_cast<const float4*>(xb + (size_t)(rd) * HW); \
            float4 x0_ = rowd_[c2], x1_ = rowd_[c2 + 1];                 \
            d0_ = float4{x0_.x - m0_.x, x0_.y - m0_.y,                   \
                         x0_.z - m0_.z, x0_.w - m0_.w};                  \
            d1_ = float4{x1_.x - m1_.x, x1_.y - m1_.y,                   \
                         x1_.z - m1_.z, x1_.w - m1_.w};                  \
        }                                                                \
    }

// stage C: h2v = h-conv(d^2); halo f4s via intra-wave shuffles
#define STAGE_C(d0_, d1_, h2v0, h2v1)                                    \
    {                                                                    \
        float4 dl_;                                                      \
        dl_.x = __shfl_up((d1_).x, 1);                                   \
        dl_.y = __shfl_up((d1_).y, 1);                                   \
        dl_.z = __shfl_up((d1_).z, 1);                                   \
        dl_.w = __shfl_up((d1_).w, 1);                                   \
        if (c == 0) dl_ = z4;                                            \
        float4 dr_;                                                      \
        dr_.x = __shfl_down((d0_).x, 1);                                 \
        dr_.y = __shfl_down((d0_).y, 1);                                 \
        dr_.z = __shfl_down((d0_).z, 1);                                 \
        dr_.w = __shfl_down((d0_).w, 1);                                 \
        if (c == 63) dr_ = z4;                                           \
        const float Xs_[16] = {                                          \
            dl_.x * dl_.x, dl_.y * dl_.y, dl_.z * dl_.z, dl_.w * dl_.w,  \
            (d0_).x * (d0_).x, (d0_).y * (d0_).y,                        \
            (d0_).z * (d0_).z, (d0_).w * (d0_).w,                        \
            (d1_).x * (d1_).x, (d1_).y * (d1_).y,                        \
            (d1_).z * (d1_).z, (d1_).w * (d1_).w,                        \
            dr_.x * dr_.x, dr_.y * dr_.y, dr_.z * dr_.z, dr_.w * dr_.w}; \
        conv9_8(Xs_, w, h2v0, h2v1);                                     \
    }

__global__ __launch_bounds__(64, 2) void lcn_kernel(const float* __restrict__ x,
                                                    float* __restrict__ out,
                                                    W9 wts) {
    const int c = threadIdx.x;          // lane 0..63, owns f4 cols 2c, 2c+1
    const int c2 = 2 * c;
    const bool pl = (c > 0), pr = (c < 63);

    // XCD swizzle: 4096 blocks = 8 XCDs x 512; 8 images per XCD, all 64
    // strips of an image co-resident on one XCD -> halo rows L2-shared.
    const int p = blockIdx.x;
    const int lid = (p & 7) * 512 + (p >> 3);
    const int img = lid >> 6;           // 0..63
    const int strip = lid & 63;         // 0..63
    const int R0 = strip * SROWS;

    const float* xb = x + (size_t)img * HW * HW;
    float* ob = out + (size_t)img * HW * HW;

    float w[9];
#pragma unroll
    for (int i = 0; i < 9; ++i) w[i] = wts.w[i];
    const float4 z4 = {0.f, 0.f, 0.f, 0.f};

    float4 hx0[8], hx1[8];   // h-conv(x) ring
    float4 q0[8], q1[8];     // h-conv(d^2) ring
    float4 dg0[4], dg1[4];   // d ring (4-step delay to output row)

    // ---- phase 1 (s = 0..7): stage A only; fill hx ring ----
#pragma unroll
    for (int pp = 0; pp < 8; ++pp) {
        const int r = R0 - 8 + pp;
        float4 hv0, hv1;
        STAGE_A(r, hv0, hv1);
        hx0[pp] = hv0; hx1[pp] = hv1;
    }

    // ---- phase 2 (s = 8..15): A + B + C; fill q ring and d ring ----
#pragma unroll
    for (int pp = 0; pp < 8; ++pp) {
        const int r = R0 + pp;          // s = 8+pp, ring phase = pp
        float4 hv0, hv1;
        STAGE_A(r, hv0, hv1);
        float4 d0, d1;
        STAGE_B(pp, r - 4, hv0, hv1, d0, d1);
        dg0[pp & 3] = d0; dg1[pp & 3] = d1;
        hx0[pp] = hv0; hx1[pp] = hv1;
        float4 h2v0, h2v1;
        STAGE_C(d0, d1, h2v0, h2v1);
        q0[pp] = h2v0; q1[pp] = h2v1;
    }

    // ---- phase 3 (s = 16..23): full pipeline, one output row per step ----
#pragma unroll
    for (int pp = 0; pp < 8; ++pp) {
        const int r = R0 + 8 + pp;      // s = 16+pp, ring phase = pp
        float4 hv0, hv1;
        STAGE_A(r, hv0, hv1);
        float4 d0, d1;
        STAGE_B(pp, r - 4, hv0, hv1, d0, d1);
        // read d(ro) (written 4 steps ago) BEFORE overwriting the slot
        float4 do0 = dg0[pp & 3], do1 = dg1[pp & 3];
        dg0[pp & 3] = d0; dg1[pp & 3] = d1;
        hx0[pp] = hv0; hx1[pp] = hv1;
        float4 h2v0, h2v1;
        STAGE_C(d0, d1, h2v0, h2v1);
        // stage D: n2(ro) = v-conv(q ring + h2v); normalize; store
        {
            float4 n0, n1;
            VRING9(q0, q1, pp, h2v0, h2v1, n0, n1);
            const int ro = r - 8;       // in [R0, R0+8)
            float4 o0, o1;
            o0.x = (n0.x > 0.25f) ? do0.x * rsqrtf(n0.x) : do0.x;
            o0.y = (n0.y > 0.25f) ? do0.y * rsqrtf(n0.y) : do0.y;
            o0.z = (n0.z > 0.25f) ? do0.z * rsqrtf(n0.z) : do0.z;
            o0.w = (n0.w > 0.25f) ? do0.w * rsqrtf(n0.w) : do0.w;
            o1.x = (n1.x > 0.25f) ? do1.x * rsqrtf(n1.x) : do1.x;
            o1.y = (n1.y > 0.25f) ? do1.y * rsqrtf(n1.y) : do1.y;
            o1.z = (n1.z > 0.25f) ? do1.z * rsqrtf(n1.z) : do1.z;
            o1.w = (n1.w > 0.25f) ? do1.w * rsqrtf(n1.w) : do1.w;
            float4* rowo = reinterpret_cast<float4*>(ob + (size_t)ro * HW);
            rowo[c2] = o0;
            rowo[c2 + 1] = o1;
        }
        q0[pp] = h2v0; q1[pp] = h2v1;
    }
}

static W9 make_w() {
    // reference: sigmah = 9/6, exponent divides by 2*sigmah = 3.0;
    // taps centered at 4.5 (asymmetric); separable: w1 = g1 / sum(g1).
    double g[9], sum = 0.0;
    for (int i = 0; i < 9; ++i) {
        double off = (double)i - 4.5;
        g[i] = exp(-(off * off) / 3.0);
        sum += g[i];
    }
    W9 r;
    for (int i = 0; i < 9; ++i) r.w[i] = (float)(g[i] / sum);
    return r;
}

extern "C" void kernel_launch(void* const* d_in, const int* in_sizes, int n_in,
                              void* d_out, int out_size, void* d_ws, size_t ws_size,
                              hipStream_t stream) {
    const float* x = (const float*)d_in[0];
    float* out = (float*)d_out;
    W9 w = make_w();
    // 64 images x 64 strips of 8 rows = 4096 blocks, 64 threads (1 wave) each.
    lcn_kernel<<<dim3(4096), dim3(64), 0, stream>>>(x, out, w);
}